// Round 1
// baseline (357.167 us; speedup 1.0000x reference)
//
#include <hip/hip_runtime.h>
#include <hip/hip_bf16.h>

// Problem constants (FieldDecoder: B=16, 64x64 tokens, DO=768, K=16x16, S=8, field 512x512)
#define DIM      768
#define NPATCH   4096          // 64*64 tokens
#define BATCH    16
#define MROWS    (BATCH*NPATCH)  // 65536
#define NCOLS    256             // 16*16 kernel taps
#define FH       512
#define FW       512

typedef __attribute__((ext_vector_type(8))) short bf16x8;   // 8 bf16 in 4 VGPRs
typedef __attribute__((ext_vector_type(4))) float f32x4;

static __device__ __forceinline__ unsigned short f2bf(float f) {
    // round-to-nearest-even fp32 -> bf16
    union { float f; unsigned int u; } v; v.f = f;
    unsigned int u = v.u;
    return (unsigned short)((u + 0x7FFFu + ((u >> 16) & 1u)) >> 16);
}

// ---------------- kernel 0: weight fp32 -> bf16 ----------------
__global__ void wconv_kernel(const float* __restrict__ w, unsigned short* __restrict__ wb) {
    int i = blockIdx.x * blockDim.x + threadIdx.x;   // one float4 per thread; 49152 threads
    float4 v = ((const float4*)w)[i];
    unsigned int p0 = (unsigned)f2bf(v.x) | ((unsigned)f2bf(v.y) << 16);
    unsigned int p1 = (unsigned)f2bf(v.z) | ((unsigned)f2bf(v.w) << 16);
    ((uint2*)wb)[i] = make_uint2(p0, p1);
}

// ---------------- kernel 1: GEMM  C[M,256] = A[M,768] (fp32) x Bw[256,768]^T (bf16) ----------------
// 128x128 tile, BK=32, 256 threads (4 waves, 2x2), each wave 64x64 via 4x4 MFMA 16x16x32.
// LDS rows padded to 40 bf16 (80 B): ds_read_b128 fragment reads are 2-way bank-aliased (free).
#define BK 32
#define LSTR 40   // bf16 units per LDS row

__global__ __launch_bounds__(256) void gemm_kernel(const float* __restrict__ A,
                                                   const unsigned short* __restrict__ Bw,
                                                   float* __restrict__ C) {
    __shared__ unsigned short sA[128 * LSTR];
    __shared__ unsigned short sB[128 * LSTR];

    const int tid  = threadIdx.x;
    const int nblk = blockIdx.x;       // 0..1   (N tiles; fastest so the 2 share A in L2)
    const int mblk = blockIdx.y;       // 0..511
    const int m0 = mblk * 128;
    const int n0 = nblk * 128;

    const int wave = tid >> 6;
    const int lane = tid & 63;
    const int wm = wave >> 1;          // 0..1
    const int wn = wave & 1;           // 0..1
    const int l15  = lane & 15;
    const int quad = lane >> 4;

    f32x4 acc[4][4] = {};

    // staging decomposition
    const int arow = tid >> 3;         // 0..31  (A: 8 lanes x float4 cover one 128B row-chunk)
    const int ac4  = tid & 7;
    const int brow = tid >> 2;         // 0..63  (B: 4 lanes x 16B cover one 64B row)
    const int bc8  = tid & 3;

    for (int k0 = 0; k0 < DIM; k0 += BK) {
        __syncthreads();
        // stage A: 128 rows x 32 fp32 -> bf16 in LDS
        #pragma unroll
        for (int p = 0; p < 4; ++p) {
            int r = arow + p * 32;
            const float4 v = *(const float4*)(A + (size_t)(m0 + r) * DIM + k0 + ac4 * 4);
            unsigned int p0 = (unsigned)f2bf(v.x) | ((unsigned)f2bf(v.y) << 16);
            unsigned int p1 = (unsigned)f2bf(v.z) | ((unsigned)f2bf(v.w) << 16);
            *(uint2*)(&sA[r * LSTR + ac4 * 4]) = make_uint2(p0, p1);
        }
        // stage B: 128 rows x 32 bf16 (already bf16 in ws; L2-resident, 384 KB total)
        #pragma unroll
        for (int p = 0; p < 2; ++p) {
            int r = brow + p * 64;
            const uint4 v = *(const uint4*)(Bw + (size_t)(n0 + r) * DIM + k0 + bc8 * 8);
            *(uint4*)(&sB[r * LSTR + bc8 * 8]) = v;
        }
        __syncthreads();

        // fragments + MFMA
        bf16x8 af[4], bf[4];
        #pragma unroll
        for (int i = 0; i < 4; ++i)
            af[i] = *(const bf16x8*)(&sA[(wm * 64 + i * 16 + l15) * LSTR + quad * 8]);
        #pragma unroll
        for (int j = 0; j < 4; ++j)
            bf[j] = *(const bf16x8*)(&sB[(wn * 64 + j * 16 + l15) * LSTR + quad * 8]);
        #pragma unroll
        for (int i = 0; i < 4; ++i)
            #pragma unroll
            for (int j = 0; j < 4; ++j)
                acc[i][j] = __builtin_amdgcn_mfma_f32_16x16x32_bf16(af[i], bf[j], acc[i][j], 0, 0, 0);
    }

    // epilogue: C/D layout col = lane&15, row = quad*4 + reg
    #pragma unroll
    for (int i = 0; i < 4; ++i) {
        #pragma unroll
        for (int j = 0; j < 4; ++j) {
            const int col = n0 + wn * 64 + j * 16 + l15;
            #pragma unroll
            for (int r = 0; r < 4; ++r) {
                const int row = m0 + wm * 64 + i * 16 + quad * 4 + r;
                C[(size_t)row * NCOLS + col] = acc[i][j][r];
            }
        }
    }
}

// ---------------- kernel 2: gather-mean into the field ----------------
// out[b,ph,pw] = mean of proj[b, (h*64+w)*256 + dh*16 + dw] over {(h,dh): clamp(8h+dh,0,511)==ph}
//                x {(w,dw): clamp(8w+dw)==pw}.  counts: 1 (p<8), 2 (8..510), 10 (p==511).
__global__ void gather_kernel(const float* __restrict__ proj, float* __restrict__ out) {
    const int id = blockIdx.x * blockDim.x + threadIdx.x;   // 16*512*512 threads
    const int b   = id >> 18;
    const int rem = id & 262143;
    const int ph  = rem >> 9;
    const int pw  = rem & 511;
    const float* p = proj + (size_t)b * (NPATCH * NCOLS);

    const int h_lo = (ph >= 8) ? ((ph - 8) >> 3) : 0;
    const int h_hi = ph >> 3;            // <= 63 always
    const int w_lo = (pw >= 8) ? ((pw - 8) >> 3) : 0;
    const int w_hi = pw >> 3;

    float sum = 0.f;
    for (int h = h_lo; h <= h_hi; ++h) {
        const int dh = ph - 8 * h;
        for (int w = w_lo; w <= w_hi; ++w) {
            const int dw = pw - 8 * w;
            sum += p[(h * 64 + w) * 256 + dh * 16 + dw];
        }
        if (pw == 511) {
            for (int dw = 8; dw < 16; ++dw)
                sum += p[(h * 64 + 63) * 256 + dh * 16 + dw];
        }
    }
    if (ph == 511) {
        for (int dh = 8; dh < 16; ++dh) {
            for (int w = w_lo; w <= w_hi; ++w) {
                const int dw = pw - 8 * w;
                sum += p[(63 * 64 + w) * 256 + dh * 16 + dw];
            }
            if (pw == 511) {
                for (int dw = 8; dw < 16; ++dw)
                    sum += p[(63 * 64 + 63) * 256 + dh * 16 + dw];
            }
        }
    }
    const int ch = (ph < 8) ? 1 : ((ph == 511) ? 10 : 2);
    const int cw = (pw < 8) ? 1 : ((pw == 511) ? 10 : 2);
    out[id] = sum / (float)(ch * cw);
}

extern "C" void kernel_launch(void* const* d_in, const int* in_sizes, int n_in,
                              void* d_out, int out_size, void* d_ws, size_t ws_size,
                              hipStream_t stream) {
    const float* tgt    = (const float*)d_in[0];   // [16, 4096, 768] fp32
    const float* weight = (const float*)d_in[1];   // [16, 16, 768]  fp32
    // d_in[2] (idx) is not needed: the fold index is recomputed analytically.
    float* out = (float*)d_out;                    // [16, 512, 512] fp32

    float* proj = (float*)d_ws;                                           // 64 MB
    unsigned short* wbf =
        (unsigned short*)((char*)d_ws + (size_t)MROWS * NCOLS * sizeof(float)); // +384 KB

    // weight -> bf16 (196608 elems / 4 per thread)
    wconv_kernel<<<192, 256, 0, stream>>>(weight, wbf);

    // GEMM: grid (N tiles fastest, so the two n-blocks of an m-tile share A via L2)
    dim3 grid(2, 512);
    gemm_kernel<<<grid, 256, 0, stream>>>(tgt, wbf, proj);

    // gather-mean: one thread per output pixel
    gather_kernel<<<(BATCH * FH * FW) / 256, 256, 0, stream>>>(proj, out);
}